// Round 15
// baseline (465.292 us; speedup 1.0000x reference)
//
#include <hip/hip_runtime.h>
#include <hip/hip_bf16.h>
#include <math.h>

#define D16   16
#define NC    64      // channels C
#define NH    8       // heads
#define CHD   128     // (C/H)*D = 8*16
#define NLAY  2
#define CEXP  256     // C*FM
#define NK    8       // rotors
#define SEQ   1024
#define BATCH 2
#define VOCAB 32000

typedef unsigned short ushort;
typedef __attribute__((ext_vector_type(8))) short short8;
typedef __attribute__((ext_vector_type(4))) short short4v;
typedef __attribute__((ext_vector_type(4))) float f32x4;

// within-wave LDS fence: drain DS queue, pin scheduler (rule #18)
#define WFENCE() do { asm volatile("s_waitcnt lgkmcnt(0)" ::: "memory"); \
                      __builtin_amdgcn_sched_barrier(0); } while (0)

// ---- Cl(3,1) sign helpers --------------------------------------------------
__device__ __forceinline__ float gp_sign(int a, int b) {
    int t = a >> 1, tot = 0;
    while (t) { tot += __popc(t & b); t >>= 1; }
    int neg = tot & 1;
    if ((a & b) & 8) neg ^= 1;   // METRIC[3] = -1
    return neg ? -1.f : 1.f;
}
__device__ __forceinline__ float rev_sign(int j) {
    int g = __popc(j);
    return ((g * (g - 1) / 2) & 1) ? -1.f : 1.f;
}
__device__ __forceinline__ ushort f2bf(float f) {
    unsigned int u = __float_as_uint(f);
    unsigned int r = (u + 0x7FFFu + ((u >> 16) & 1u)) >> 16;
    return (ushort)r;
}
__device__ __forceinline__ float bf2f(ushort h) {
    return __uint_as_float((unsigned int)h << 16);
}

// ---- merged prep: split_hw | embed+PE | split_lw | tmix --------------------
__global__ void prep_kernel(const int* __restrict__ tok, const float* __restrict__ embed,
                            float* __restrict__ x,
                            const float* __restrict__ rotor_biv, const float* __restrict__ mixw,
                            float* __restrict__ Tmix,
                            const float* __restrict__ hw,
                            ushort* __restrict__ hwh, ushort* __restrict__ hwl,
                            const float* __restrict__ wq, const float* __restrict__ wk,
                            const float* __restrict__ wv, const float* __restrict__ wo,
                            const float* __restrict__ up, const float* __restrict__ dn,
                            ushort* __restrict__ wsp) {
    int bid = blockIdx.x;
    if (bid < 8000) {
        int idx = bid * 256 + threadIdx.x;
        float f = hw[idx];
        ushort hi = f2bf(f);
        hwh[idx] = hi;
        hwl[idx] = f2bf(f - bf2f(hi));
    } else if (bid < 8512) {
        int idx = (bid - 8000) * 256 + threadIdx.x;   // < 131072
        int c  = idx & (NC - 1);
        int bl = idx / NC;
        int l  = bl & (SEQ - 1);
        int t  = tok[bl];
        const float* e = embed + ((size_t)t * NC + c) * D16;
        float v[D16];
#pragma unroll
        for (int j = 0; j < D16; j++) v[j] = e[j];
        float freq = exp2f(-(float)c * (13.287712379549449f / (float)NC));
        float theta = (float)l * freq;
        float sn, cs;
        __sincosf(theta, &sn, &cs);
        float tmp[D16], out[D16];
#pragma unroll
        for (int k = 0; k < D16; k++)
            tmp[k] = cs * v[k] + sn * gp_sign(3, 3 ^ k) * v[3 ^ k];
#pragma unroll
        for (int k = 0; k < D16; k++)
            out[k] = cs * tmp[k] - sn * gp_sign(k ^ 3, 3) * tmp[k ^ 3];
        float* xp = x + (size_t)idx * D16;
#pragma unroll
        for (int j = 0; j < D16; j++) xp[j] = out[j];
    } else if (bid < 8896) {
        int idx = (bid - 8512) * 256 + threadIdx.x;   // < 98304
        const float* src; ushort *dh, *dl; int off;
        if (idx < 8192)       { src = wq; off = idx;         dh = wsp;          dl = wsp + 8192; }
        else if (idx < 16384) { src = wk; off = idx - 8192;  dh = wsp + 16384;  dl = wsp + 24576; }
        else if (idx < 24576) { src = wv; off = idx - 16384; dh = wsp + 32768;  dl = wsp + 40960; }
        else if (idx < 32768) { src = wo; off = idx - 24576; dh = wsp + 49152;  dl = wsp + 57344; }
        else if (idx < 65536) { src = up; off = idx - 32768; dh = wsp + 65536;  dl = wsp + 98304; }
        else                  { src = dn; off = idx - 65536; dh = wsp + 131072; dl = wsp + 163840; }
        float f = src[off];
        ushort hi = f2bf(f);
        dh[off] = hi;
        dl[off] = f2bf(f - bf2f(hi));
    } else {
        int lay = bid - 8896;
        __shared__ float rot[NK][D16];
        __shared__ float w[NK];
        int t = threadIdx.x;
        if (t < NK) {
            const int BIV[6] = { 3, 5, 6, 9, 10, 12 };
            float r[D16];
#pragma unroll
            for (int j = 0; j < D16; j++) r[j] = 0.f;
            r[0] = 1.f;
            float nrm = 1.f;
            for (int i = 0; i < 6; i++) {
                float bv = rotor_biv[(lay * NK + t) * 6 + i];
                r[BIV[i]] = bv; nrm += bv * bv;
            }
            nrm = sqrtf(nrm);
            for (int j = 0; j < D16; j++) rot[t][j] = r[j] / nrm;
        }
        if (t == 0) {
            float mx = -INFINITY;
            for (int kk = 0; kk < NK; kk++) mx = fmaxf(mx, mixw[lay * NK + kk]);
            float s = 0.f, e[NK];
            for (int kk = 0; kk < NK; kk++) { e[kk] = expf(mixw[lay * NK + kk] - mx); s += e[kk]; }
            for (int kk = 0; kk < NK; kk++) w[kk] = e[kk] / s;
        }
        __syncthreads();
        int j = t >> 4, p = t & 15;
        float acc = 0.f;
        for (int kk = 0; kk < NK; kk++) {
            float tk = 0.f;
            for (int i = 0; i < D16; i++) {
                int n = i ^ j ^ p;
                float rn = rot[kk][n] * rev_sign(n);
                tk += rot[kk][i] * rn * gp_sign(i, j) * gp_sign(i ^ j, n);
            }
            acc += w[kk] * tk;
        }
        Tmix[lay * 256 + t] = acc;
    }
}

// ---- MFMA qkv: CLN fused; outputs restaged in LDS -> vectorized stores -----
__global__ __launch_bounds__(256) void qkv_mfma_kernel(
        const float* __restrict__ x, const float* __restrict__ g,
        const ushort* __restrict__ wqh, const ushort* __restrict__ wql,
        const ushort* __restrict__ wkh, const ushort* __restrict__ wkl,
        const ushort* __restrict__ wvh, const ushort* __restrict__ wvl,
        ushort* __restrict__ qh_, ushort* __restrict__ ql_,
        ushort* __restrict__ kh_, ushort* __restrict__ kl_,
        ushort* __restrict__ vh_, ushort* __restrict__ vl_) {
    __shared__ float xlds[4][1024];
    __shared__ float glds[64];
    int t = threadIdx.x, wave = t >> 6, lane = t & 63;
    int tok = blockIdx.x * 4 + wave;
    glds[lane] = g[lane];              // per-wave redundant (benign)
    float ssum = 0.f;
    {
        const float* src = x + (size_t)tok * 1024 + lane * 16;
        float* dst = &xlds[wave][lane * 16];
#pragma unroll
        for (int i = 0; i < 4; i++) {
            float4 vv = *(const float4*)(src + i * 4);
            *(float4*)(dst + i * 4) = vv;
            ssum += vv.x * vv.x + vv.y * vv.y + vv.z * vv.z + vv.w * vv.w;
        }
    }
#pragma unroll
    for (int off = 32; off > 0; off >>= 1) ssum += __shfl_xor(ssum, off);
    float inv = 1.f / sqrtf(ssum * (1.f / 1024.f) + 1e-6f);
    WFENCE();

    int dn = lane & 15, kg = lane >> 4;
    short8 bfh[2], bfl[2];
#pragma unroll
    for (int ks = 0; ks < 2; ks++) {
        int c0 = ks * 32 + kg * 8;
#pragma unroll
        for (int i = 0; i < 8; i++) {
            float val = xlds[wave][(c0 + i) * 16 + dn] * inv * glds[c0 + i];
            ushort hi = f2bf(val);
            bfh[ks][i] = (short)hi;
            bfl[ks][i] = (short)f2bf(val - bf2f(hi));
        }
    }

    const ushort* Wh[3] = { wqh, wkh, wvh };
    const ushort* Wl[3] = { wql, wkl, wvl };
    ushort* Oh[3] = { qh_, kh_, vh_ };
    ushort* Ol[3] = { ql_, kl_, vl_ };
#pragma unroll
    for (int m = 0; m < 3; m++) {
        f32x4 accs[4];
#pragma unroll
        for (int Mt = 0; Mt < 4; Mt++) {
            f32x4 acc = (f32x4){0.f, 0.f, 0.f, 0.f};
#pragma unroll
            for (int ks = 0; ks < 2; ks++) {
                size_t aoff = (size_t)(Mt * 16 + dn) * 64 + ks * 32 + kg * 8;
                short8 ah = *(const short8*)(Wh[m] + aoff);
                short8 al = *(const short8*)(Wl[m] + aoff);
                acc = __builtin_amdgcn_mfma_f32_16x16x32_bf16(ah, bfh[ks], acc, 0, 0, 0);
                acc = __builtin_amdgcn_mfma_f32_16x16x32_bf16(ah, bfl[ks], acc, 0, 0, 0);
                acc = __builtin_amdgcn_mfma_f32_16x16x32_bf16(al, bfh[ks], acc, 0, 0, 0);
            }
            accs[Mt] = acc;
        }
        WFENCE();
#pragma unroll
        for (int Mt = 0; Mt < 4; Mt++)
#pragma unroll
            for (int j = 0; j < 4; j++)
                xlds[wave][(Mt * 16 + kg * 4 + j) * 16 + dn] = accs[Mt][j];
        WFENCE();
        {
            const float* row = &xlds[wave][lane * 16];
            float vals[16];
#pragma unroll
            for (int i4 = 0; i4 < 4; i4++) {
                float4 vv = *(const float4*)(row + i4 * 4);
                vals[i4 * 4 + 0] = vv.x; vals[i4 * 4 + 1] = vv.y;
                vals[i4 * 4 + 2] = vv.z; vals[i4 * 4 + 3] = vv.w;
            }
            if (m == 0) {
#pragma unroll
                for (int e = 0; e < 16; e++)
                    vals[e] *= gp_sign(e, e) * 0.088388347648318447f;
            }
            short8 h0, h1, l0, l1;
#pragma unroll
            for (int e = 0; e < 8; e++) {
                ushort hi = f2bf(vals[e]);
                h0[e] = (short)hi; l0[e] = (short)f2bf(vals[e] - bf2f(hi));
                ushort hi2 = f2bf(vals[e + 8]);
                h1[e] = (short)hi2; l1[e] = (short)f2bf(vals[e + 8] - bf2f(hi2));
            }
            size_t ob = (size_t)tok * 1024 + lane * 16;
            *(short8*)(Oh[m] + ob) = h0;
            *(short8*)(Oh[m] + ob + 8) = h1;
            *(short8*)(Ol[m] + ob) = l0;
            *(short8*)(Ol[m] + ob + 8) = l1;
        }
    }
}

// ---- MFMA flash attention v2: Q-tile 32 (2 waves), KV-tile 32 --------------
// grid (32, 16); block 128 = 2 waves; 37KB LDS -> 4 blocks/CU
__global__ __launch_bounds__(128) void attn_mfma_kernel(
        const ushort* __restrict__ qh_, const ushort* __restrict__ ql_,
        const ushort* __restrict__ kh_, const ushort* __restrict__ kl_,
        const ushort* __restrict__ vh_, const ushort* __restrict__ vl_,
        float* __restrict__ o) {
    int qi = 31 - blockIdx.x;         // longest jobs dispatched first
    int bh = blockIdx.y;
    int b = bh >> 3, h = bh & 7;
    int t = threadIdx.x;
    int wave = t >> 6, lane = t & 63;
    int lq = lane & 15, lk4 = lane >> 4;

    __shared__ __align__(16) ushort Kh[32 * 128], Kl[32 * 128];
    __shared__ __align__(16) ushort Vh[128 * 32], Vl[128 * 32];
    __shared__ __align__(16) ushort Ph[2][16 * 40], Pl[2][16 * 40];

    int qrow = qi * 32 + wave * 16 + lq;

    short8 qfh[4], qfl[4];
    {
        const ushort* qb = qh_ + (size_t)(b * SEQ + qrow) * 1024 + h * CHD;
        const ushort* qb2 = ql_ + (size_t)(b * SEQ + qrow) * 1024 + h * CHD;
#pragma unroll
        for (int ks = 0; ks < 4; ks++) {
            qfh[ks] = *(const short8*)(qb + ks * 32 + lk4 * 8);
            qfl[ks] = *(const short8*)(qb2 + ks * 32 + lk4 * 8);
        }
    }

    // staging geometry (128 threads)
    int kr = t >> 2, kcb = (t & 3) * 32;      // K: row k (0..31), col-base d
    int vk = t >> 2, vd0 = (t & 3) * 32;      // V: row k (0..31), d-base
    int kswz = (kr & 7) << 3;

    short8 pk_h[4], pk_l[4], pv_h[4], pv_l[4];

    {
        const ushort* sh_ = kh_ + (size_t)(b * SEQ + kr) * 1024 + h * CHD + kcb;
        const ushort* sl_ = kl_ + (size_t)(b * SEQ + kr) * 1024 + h * CHD + kcb;
#pragma unroll
        for (int j = 0; j < 4; j++) {
            pk_h[j] = *(const short8*)(sh_ + j * 8);
            pk_l[j] = *(const short8*)(sl_ + j * 8);
        }
        const ushort* vhp = vh_ + (size_t)(b * SEQ + vk) * 1024 + h * CHD + vd0;
        const ushort* vlp = vl_ + (size_t)(b * SEQ + vk) * 1024 + h * CHD + vd0;
#pragma unroll
        for (int j = 0; j < 4; j++) {
            pv_h[j] = *(const short8*)(vhp + j * 8);
            pv_l[j] = *(const short8*)(vlp + j * 8);
        }
    }

    float m_run = -1e30f, l_run = 0.f;
    f32x4 oacc[8];
#pragma unroll
    for (int m = 0; m < 8; m++) oacc[m] = (f32x4){0.f, 0.f, 0.f, 0.f};

    int T = qi + 1;                    // k-tiles of 32
    for (int kti = 0; kti < T; kti++) {
        __syncthreads();
        // K regs -> LDS (swizzled row-major [32][128])
#pragma unroll
        for (int j = 0; j < 4; j++) {
            int c8 = kcb + j * 8;
            *(short8*)&Kh[kr * 128 + (c8 ^ kswz)] = pk_h[j];
            *(short8*)&Kl[kr * 128 + (c8 ^ kswz)] = pk_l[j];
        }
        // V regs -> LDS transposed: (k=vk, d) -> Vh[d*32 + (vk ^ ((d&3)<<3))]
#pragma unroll
        for (int j = 0; j < 4; j++)
#pragma unroll
            for (int e = 0; e < 8; e++) {
                int d = vd0 + j * 8 + e;
                int addr = d * 32 + (vk ^ ((d & 3) << 3));
                Vh[addr] = (ushort)pv_h[j][e];
                Vl[addr] = (ushort)pv_l[j][e];
            }
        __syncthreads();

        // prefetch next tile (overlaps MFMA below)
        if (kti + 1 < T) {
            const ushort* sh_ = kh_ + (size_t)(b * SEQ + (kti + 1) * 32 + kr) * 1024 + h * CHD + kcb;
            const ushort* sl_ = kl_ + (size_t)(b * SEQ + (kti + 1) * 32 + kr) * 1024 + h * CHD + kcb;
#pragma unroll
            for (int j = 0; j < 4; j++) {
                pk_h[j] = *(const short8*)(sh_ + j * 8);
                pk_l[j] = *(const short8*)(sl_ + j * 8);
            }
            const ushort* vhp = vh_ + (size_t)(b * SEQ + (kti + 1) * 32 + vk) * 1024 + h * CHD + vd0;
            const ushort* vlp = vl_ + (size_t)(b * SEQ + (kti + 1) * 32 + vk) * 1024 + h * CHD + vd0;
#pragma unroll
            for (int j = 0; j < 4; j++) {
                pv_h[j] = *(const short8*)(vhp + j * 8);
                pv_l[j] = *(const short8*)(vlp + j * 8);
            }
        }

        // ---- scores: S^T tiles (16 k x 16 q), 2 kt ----
        f32x4 s[2];
#pragma unroll
        for (int kt = 0; kt < 2; kt++) s[kt] = (f32x4){0.f, 0.f, 0.f, 0.f};
#pragma unroll
        for (int kt = 0; kt < 2; kt++) {
            int rr = kt * 16 + lq;
            int rswz = (rr & 7) << 3;
#pragma unroll
            for (int ks = 0; ks < 4; ks++) {
                int idx = rr * 128 + ((ks * 32 + lk4 * 8) ^ rswz);
                short8 kfh = *(const short8*)&Kh[idx];
                short8 kfl = *(const short8*)&Kl[idx];
                s[kt] = __builtin_amdgcn_mfma_f32_16x16x32_bf16(kfh, qfh[ks], s[kt], 0, 0, 0);
                s[kt] = __builtin_amdgcn_mfma_f32_16x16x32_bf16(kfl, qfh[ks], s[kt], 0, 0, 0);
                s[kt] = __builtin_amdgcn_mfma_f32_16x16x32_bf16(kfh, qfl[ks], s[kt], 0, 0, 0);
            }
        }

        // causal mask on diagonal tile
        if (kti == qi) {
#pragma unroll
            for (int kt = 0; kt < 2; kt++)
#pragma unroll
                for (int r = 0; r < 4; r++) {
                    int kg = kti * 32 + kt * 16 + lk4 * 4 + r;
                    if (kg > qrow) s[kt][r] = -1e30f;
                }
        }

        // ---- online softmax (8 scores/lane for q-col lq) ----
        float tm = -1e30f;
#pragma unroll
        for (int kt = 0; kt < 2; kt++)
#pragma unroll
            for (int r = 0; r < 4; r++) tm = fmaxf(tm, s[kt][r]);
        tm = fmaxf(tm, __shfl_xor(tm, 16));
        tm = fmaxf(tm, __shfl_xor(tm, 32));
        float mnew = fmaxf(m_run, tm);
        float corr = __expf(m_run - mnew);
        float ts = 0.f;
#pragma unroll
        for (int kt = 0; kt < 2; kt++) {
            float p0 = __expf(s[kt][0] - mnew);
            float p1 = __expf(s[kt][1] - mnew);
            float p2 = __expf(s[kt][2] - mnew);
            float p3 = __expf(s[kt][3] - mnew);
            ts += (p0 + p1) + (p2 + p3);
            short4v hi4, lo4;
            ushort u0 = f2bf(p0); hi4[0] = (short)u0; lo4[0] = (short)f2bf(p0 - bf2f(u0));
            ushort u1 = f2bf(p1); hi4[1] = (short)u1; lo4[1] = (short)f2bf(p1 - bf2f(u1));
            ushort u2 = f2bf(p2); hi4[2] = (short)u2; lo4[2] = (short)f2bf(p2 - bf2f(u2));
            ushort u3 = f2bf(p3); hi4[3] = (short)u3; lo4[3] = (short)f2bf(p3 - bf2f(u3));
            int pidx = lq * 40 + kt * 16 + lk4 * 4;
            *(short4v*)&Ph[wave][pidx] = hi4;
            *(short4v*)&Pl[wave][pidx] = lo4;
        }
        ts += __shfl_xor(ts, 16);
        ts += __shfl_xor(ts, 32);
        l_run = l_run * corr + ts;
        m_run = mnew;
#pragma unroll
        for (int m = 0; m < 8; m++) oacc[m] *= corr;

        WFENCE();   // P visible within wave
        short8 pfh = *(const short8*)&Ph[wave][lq * 40 + lk4 * 8];
        short8 pfl = *(const short8*)&Pl[wave][lq * 40 + lk4 * 8];
#pragma unroll
        for (int m = 0; m < 8; m++) {
            int vrr = m * 16 + lq;
            int idx = vrr * 32 + ((lk4 * 8) ^ ((vrr & 3) << 3));
            short8 vfh = *(const short8*)&Vh[idx];
            short8 vfl = *(const short8*)&Vl[idx];
            oacc[m] = __builtin_amdgcn_mfma_f32_16x16x32_bf16(vfh, pfh, oacc[m], 0, 0, 0);
            oacc[m] = __builtin_amdgcn_mfma_f32_16x16x32_bf16(vfl, pfh, oacc[m], 0, 0, 0);
            oacc[m] = __builtin_amdgcn_mfma_f32_16x16x32_bf16(vfh, pfl, oacc[m], 0, 0, 0);
        }
    }

    float invl = 1.f / l_run;
    float* ob = o + (size_t)(b * SEQ + qrow) * 1024 + h * CHD;
#pragma unroll
    for (int m = 0; m < 8; m++) {
        float4 w;
        w.x = oacc[m][0] * invl; w.y = oacc[m][1] * invl;
        w.z = oacc[m][2] * invl; w.w = oacc[m][3] * invl;
        *(float4*)(ob + m * 16 + lk4 * 4) = w;
    }
}

// ---- fused MFMA proj+rms+Tmix+FFN; single vectorized x write ---------------
__global__ __launch_bounds__(256) void proj_ffn_mfma_kernel(
        const float* __restrict__ o_in,
        const ushort* __restrict__ woh, const ushort* __restrict__ wol,
        const float* __restrict__ g2, const float* __restrict__ Tmix,
        const ushort* __restrict__ uph, const ushort* __restrict__ upl,
        const ushort* __restrict__ dnh, const ushort* __restrict__ dnl,
        float* __restrict__ x) {
    __shared__ float olds[4][1024];
    __shared__ float xnlds[4][1024];
    __shared__ float g2lds[64];
    __shared__ float Ttlds[256];
    __shared__ ushort xmh[4][16][72], xml[4][16][72];
    __shared__ ushort ghh[4][16][72], ghl[4][16][72];
    int t = threadIdx.x, wave = t >> 6, lane = t & 63;
    int tok = blockIdx.x * 4 + wave;
    g2lds[lane] = g2[lane];
#pragma unroll
    for (int i = lane; i < 256; i += 64)
        Ttlds[i] = Tmix[(i & 15) * 16 + (i >> 4)];
    {
        const float* src = o_in + (size_t)tok * 1024 + lane * 16;
        const float* srx = x + (size_t)tok * 1024 + lane * 16;
        float* dst = &olds[wave][lane * 16];
        float* dsx = &xnlds[wave][lane * 16];
#pragma unroll
        for (int i = 0; i < 4; i++) {
            *(float4*)(dst + i * 4) = *(const float4*)(src + i * 4);
            *(float4*)(dsx + i * 4) = *(const float4*)(srx + i * 4);
        }
    }
    WFENCE();

    int dn = lane & 15, kg = lane >> 4;
    short8 bfh[2], bfl[2];
#pragma unroll
    for (int ks = 0; ks < 2; ks++) {
        int c0 = ks * 32 + kg * 8;
#pragma unroll
        for (int i = 0; i < 8; i++) {
            float val = olds[wave][(c0 + i) * 16 + dn];
            ushort hi = f2bf(val);
            bfh[ks][i] = (short)hi;
            bfl[ks][i] = (short)f2bf(val - bf2f(hi));
        }
    }

    f32x4 C1[4];
#pragma unroll
    for (int Mt = 0; Mt < 4; Mt++) {
        f32x4 acc = (f32x4){0.f, 0.f, 0.f, 0.f};
#pragma unroll
        for (int ks = 0; ks < 2; ks++) {
            size_t aoff = (size_t)(Mt * 16 + dn) * 64 + ks * 32 + kg * 8;
            short8 ah = *(const short8*)(woh + aoff);
            short8 al = *(const short8*)(wol + aoff);
            acc = __builtin_amdgcn_mfma_f32_16x16x32_bf16(ah, bfh[ks], acc, 0, 0, 0);
            acc = __builtin_amdgcn_mfma_f32_16x16x32_bf16(ah, bfl[ks], acc, 0, 0, 0);
            acc = __builtin_amdgcn_mfma_f32_16x16x32_bf16(al, bfh[ks], acc, 0, 0, 0);
        }
        C1[Mt] = acc;
    }

    float ssum = 0.f;
#pragma unroll
    for (int Mt = 0; Mt < 4; Mt++) {
#pragma unroll
        for (int j = 0; j < 4; j++) {
            int idx = (Mt * 16 + kg * 4 + j) * 16 + dn;
            float r = xnlds[wave][idx] + C1[Mt][j];
            xnlds[wave][idx] = r;
            ssum += r * r;
        }
    }
#pragma unroll
    for (int off = 32; off > 0; off >>= 1) ssum += __shfl_xor(ssum, off);
    float inv2 = 1.f / sqrtf(ssum * (1.f / 1024.f) + 1e-6f);
    WFENCE();

    const float4* tr = (const float4*)&Ttlds[dn * 16];
    float4 t0 = tr[0], t1 = tr[1], t2 = tr[2], t3 = tr[3];
#pragma unroll
    for (int half = 0; half < 2; half++) {
        short8 xh, xl;
#pragma unroll
        for (int cc = 0; cc < 8; cc++) {
            int c = kg * 16 + half * 8 + cc;
            const float4* xr = (const float4*)&xnlds[wave][c * 16];
            float4 x0 = xr[0], x1 = xr[1], x2 = xr[2], x3 = xr[3];
            float dot = x0.x * t0.x + x0.y * t0.y + x0.z * t0.z + x0.w * t0.w
                      + x1.x * t1.x + x1.y * t1.y + x1.z * t1.z + x1.w * t1.w
                      + x2.x * t2.x + x2.y * t2.y + x2.z * t2.z + x2.w * t2.w
                      + x3.x * t3.x + x3.y * t3.y + x3.z * t3.z + x3.w * t3.w;
            float xm = dot * inv2 * g2lds[c];
            ushort hi = f2bf(xm);
            xh[cc] = (short)hi;
            xl[cc] = (short)f2bf(xm - bf2f(hi));
        }
        *(short8*)&xmh[wave][dn][kg * 16 + half * 8] = xh;
        *(short8*)&xml[wave][dn][kg * 16 + half * 8] = xl;
    }
    WFENCE();

    int p = dn;
    short8 bxh[2], bxl[2];
#pragma unroll
    for (int ks = 0; ks < 2; ks++) {
        bxh[ks] = *(const short8*)&xmh[wave][p][ks * 32 + kg * 8];
        bxl[ks] = *(const short8*)&xml[wave][p][ks * 32 + kg * 8];
    }

    f32x4 Cout[4];
#pragma unroll
    for (int m = 0; m < 4; m++) Cout[m] = (f32x4){0.f, 0.f, 0.f, 0.f};

    const float kA = 0.7978845608028654f;
#pragma unroll
    for (int ec = 0; ec < 4; ec++) {
        f32x4 accU[4];
#pragma unroll
        for (int mt = 0; mt < 4; mt++) {
            f32x4 acc = (f32x4){0.f, 0.f, 0.f, 0.f};
#pragma unroll
            for (int ks = 0; ks < 2; ks++) {
                size_t aoff = (size_t)(ec * 64 + mt * 16 + p) * 64 + ks * 32 + kg * 8;
                short8 ah = *(const short8*)(uph + aoff);
                short8 al = *(const short8*)(upl + aoff);
                acc = __builtin_amdgcn_mfma_f32_16x16x32_bf16(ah, bxh[ks], acc, 0, 0, 0);
                acc = __builtin_amdgcn_mfma_f32_16x16x32_bf16(ah, bxl[ks], acc, 0, 0, 0);
                acc = __builtin_amdgcn_mfma_f32_16x16x32_bf16(al, bxh[ks], acc, 0, 0, 0);
            }
            accU[mt] = acc;
        }
        WFENCE();
#pragma unroll
        for (int mt = 0; mt < 4; mt++) {
#pragma unroll
            for (int j = 0; j < 4; j++) {
                int eloc = mt * 16 + kg * 4 + j;
                float u = accU[mt][j];
                float z = kA * (u + 0.044715f * u * u * u);
                float ex = __expf(2.f * z);
                float gg = u - u * (1.f / (ex + 1.f));
                ushort hi = f2bf(gg);
                ghh[wave][p][eloc] = hi;
                ghl[wave][p][eloc] = f2bf(gg - bf2f(hi));
            }
        }
        WFENCE();
#pragma unroll
        for (int mto = 0; mto < 4; mto++) {
#pragma unroll
            for (int ks2 = 0; ks2 < 2; ks2++) {
                size_t aoff = (size_t)(mto * 16 + p) * 256 + ec * 64 + ks2 * 32 + kg * 8;
                short8 ah = *(const short8*)(dnh + aoff);
                short8 al = *(const short8*)(dnl + aoff);
                short8 bgh = *(const short8*)&ghh[wave][p][ks2 * 32 + kg * 8];
                short8 bgl = *(const short8*)&ghl[wave][p][ks2 * 32 + kg * 8];
                Cout[mto] = __builtin_amdgcn_mfma_f32_16x16x32_bf16(ah, bgh, Cout[mto], 0, 0, 0);
                Cout[mto] = __builtin_amdgcn_mfma_f32_16x16x32_bf16(ah, bgl, Cout[mto], 0, 0, 0);
                Cout[mto] = __builtin_amdgcn_mfma_f32_16x16x32_bf16(al, bgh, Cout[mto], 0, 0, 0);
            }
        }
    }

    WFENCE();
#pragma unroll
    for (int mto = 0; mto < 4; mto++)
#pragma unroll
        for (int j = 0; j < 4; j++)
            olds[wave][(mto * 16 + kg * 4 + j) * 16 + p] = Cout[mto][j];
    WFENCE();
    {
        const float* rx = &xnlds[wave][lane * 16];
        const float* rc = &olds[wave][lane * 16];
        float* dst = x + (size_t)tok * 1024 + lane * 16;
#pragma unroll
        for (int i = 0; i < 4; i++) {
            float4 a = *(const float4*)(rx + i * 4);
            float4 bb = *(const float4*)(rc + i * 4);
            float4 w;
            w.x = a.x + bb.x; w.y = a.y + bb.y;
            w.z = a.z + bb.z; w.w = a.w + bb.w;
            *(float4*)(dst + i * 4) = w;
        }
    }
}

// ---- final norm + blade gate + grade-0; emit bf16 hi/lo --------------------
__global__ void g0_kernel(const float* __restrict__ x,
                          const float* __restrict__ g,
                          const float* __restrict__ sel,
                          ushort* __restrict__ g0h,
                          ushort* __restrict__ g0l) {
    int bl = blockIdx.x;
    const float* xr = x + (size_t)bl * 1024;
    __shared__ float red[256];
    float s = 0.f;
    for (int i = threadIdx.x; i < 1024; i += 256) { float v = xr[i]; s += v * v; }
    red[threadIdx.x] = s; __syncthreads();
    for (int st = 128; st > 0; st >>= 1) {
        if (threadIdx.x < st) red[threadIdx.x] += red[threadIdx.x + st];
        __syncthreads();
    }
    float inv = 1.f / sqrtf(red[0] * (1.f / 1024.f) + 1e-6f);
    if (threadIdx.x < NC) {
        int c = threadIdx.x;
        float gate = 1.f / (1.f + expf(-sel[c * D16]));
        float val = xr[c * D16] * inv * g[c] * gate;
        ushort hi = f2bf(val);
        g0h[(size_t)bl * NC + c] = hi;
        g0l[(size_t)bl * NC + c] = f2bf(val - bf2f(hi));
    }
}

// ---- head GEMM: 64 rows x 256 vocab cols per block; 1KB/wave stores --------
__global__ __launch_bounds__(256) void head_mfma_kernel(
        const ushort* __restrict__ g0h, const ushort* __restrict__ g0l,
        const ushort* __restrict__ hwh, const ushort* __restrict__ hwl,
        const float* __restrict__ hb, float* __restrict__ out) {
    int t = threadIdx.x;
    int wave = t >> 6, lane = t & 63;
    int lr = lane & 15, lk = lane >> 4;
    int rowbase = blockIdx.y * 64 + wave * 16;
    int vbase = blockIdx.x * 256;

    __shared__ float tile[64 * 264];

    short8 ah[2], al[2];
#pragma unroll
    for (int ks = 0; ks < 2; ks++) {
        size_t off = (size_t)(rowbase + lr) * NC + ks * 32 + lk * 8;
        ah[ks] = *(const short8*)(g0h + off);
        al[ks] = *(const short8*)(g0l + off);
    }
    f32x4 acc[16];
#pragma unroll
    for (int nt = 0; nt < 16; nt++) acc[nt] = (f32x4){0.f, 0.f, 0.f, 0.f};

#pragma unroll
    for (int ks = 0; ks < 2; ks++) {
#pragma unroll
        for (int nt = 0; nt < 16; nt++) {
            size_t boff = (size_t)(vbase + nt * 16 + lr) * NC + ks * 32 + lk * 8;
            short8 bh = *(const short8*)(hwh + boff);
            short8 bl = *(const short8*)(hwl + boff);
            acc[nt] = __builtin_amdgcn_mfma_f32_16x16x32_bf16(ah[ks], bh, acc[nt], 0, 0, 0);
            acc[nt] = __builtin_amdgcn_mfma_f32_16x16x32_bf16(ah[ks], bl, acc[nt], 0, 0, 0);
            acc[nt] = __builtin_amdgcn_mfma_f32_16x16x32_bf16(al[ks], bh, acc[nt], 0, 0, 0);
        }
    }

#pragma unroll
    for (int nt = 0; nt < 16; nt++)
#pragma unroll
        for (int r = 0; r < 4; r++)
            tile[(wave * 16 + lk * 4 + r) * 264 + nt * 16 + lr] = acc[nt][r];
    __syncthreads();

    float4 bias4 = *(const float4*)(hb + vbase + lane * 4);
#pragma unroll
    for (int iter = 0; iter < 16; iter++) {
        int row = iter * 4 + wave;
        float4 vv = *(const float4*)&tile[row * 264 + lane * 4];
        f32x4 sv;
        sv[0] = vv.x + bias4.x; sv[1] = vv.y + bias4.y;
        sv[2] = vv.z + bias4.z; sv[3] = vv.w + bias4.w;
        __builtin_nontemporal_store(sv,
            (f32x4*)(out + (size_t)(blockIdx.y * 64 + row) * VOCAB + vbase + lane * 4));
    }
}

extern "C" void kernel_launch(void* const* d_in, const int* in_sizes, int n_in,
                              void* d_out, int out_size, void* d_ws, size_t ws_size,
                              hipStream_t stream) {
    (void)in_sizes; (void)n_in; (void)out_size; (void)ws_size;
    const int*   tok      = (const int*)  d_in[0];
    const float* embed    = (const float*)d_in[1];
    const float* ln1_g    = (const float*)d_in[2];
    const float* ln2_g    = (const float*)d_in[3];
    const float* wq       = (const float*)d_in[4];
    const float* wk       = (const float*)d_in[5];
    const float* wv       = (const float*)d_in[6];
    const float* wo       = (const float*)d_in[7];
    const float* ffn_up   = (const float*)d_in[8];
    const float* ffn_down = (const float*)d_in[9];
    const float* rotor    = (const float*)d_in[10];
    const float* mixw     = (const float*)d_in[11];
    const float* out_ln_g = (const float*)d_in[12];
    const float* sel      = (const float*)d_in[13];
    const float* head_w   = (const float*)d_in[14];
    const float* head_b   = (const float*)d_in[15];
    float* out = (float*)d_out;

    float* ws  = (float*)d_ws;
    float* x    = ws;                         // 2,097,152 f
    float* o    = x + 2097152;                // 2,097,152 f
    float* Tmx  = o + 2097152;                // 512 f
    ushort* qh   = (ushort*)(Tmx + 512);      // 2,097,152 us each
    ushort* ql   = qh + 2097152;
    ushort* kh   = ql + 2097152;
    ushort* kl   = kh + 2097152;
    ushort* vh   = kl + 2097152;
    ushort* vl   = vh + 2097152;
    ushort* g0h  = vl + 2097152;              // 131,072
    ushort* g0l  = g0h + 131072;
    ushort* hwh  = g0l + 131072;              // 2,048,000
    ushort* hwl  = hwh + 2048000;
    ushort* wsp  = hwl + 2048000;             // 196,608

    prep_kernel<<<8898, 256, 0, stream>>>(tok, embed, x, rotor, mixw, Tmx,
                                          head_w, hwh, hwl,
                                          wq, wk, wv, wo, ffn_up, ffn_down, wsp);

    for (int l = 0; l < NLAY; l++) {
        int lo = l * 4096;
        int le = l * 16384;
        qkv_mfma_kernel<<<512, 256, 0, stream>>>(
            x, ln1_g + l * NC,
            wsp + lo, wsp + 8192 + lo, wsp + 16384 + lo, wsp + 24576 + lo,
            wsp + 32768 + lo, wsp + 40960 + lo,
            qh, ql, kh, kl, vh, vl);
        dim3 ag(32, 16);
        attn_mfma_kernel<<<ag, 128, 0, stream>>>(qh, ql, kh, kl, vh, vl, o);
        proj_ffn_mfma_kernel<<<512, 256, 0, stream>>>(
            o, wsp + 49152 + lo, wsp + 57344 + lo,
            ln2_g + l * NC, Tmx + l * 256,
            wsp + 65536 + le, wsp + 98304 + le,
            wsp + 131072 + le, wsp + 163840 + le, x);
    }

    g0_kernel<<<BATCH * SEQ, 256, 0, stream>>>(x, out_ln_g, sel, g0h, g0l);
    dim3 hg(VOCAB / 256, (BATCH * SEQ) / 64);   // (125, 32)
    head_mfma_kernel<<<hg, 256, 0, stream>>>(g0h, g0l, hwh, hwl, head_b, out);
}

// Round 16
// 425.799 us; speedup vs baseline: 1.0928x; 1.0928x over previous
//
#include <hip/hip_runtime.h>
#include <hip/hip_bf16.h>
#include <math.h>

#define D16   16
#define NC    64      // channels C
#define NH    8       // heads
#define CHD   128     // (C/H)*D = 8*16
#define NLAY  2
#define CEXP  256     // C*FM
#define NK    8       // rotors
#define SEQ   1024
#define BATCH 2
#define VOCAB 32000

typedef unsigned short ushort;
typedef __attribute__((ext_vector_type(8))) short short8;
typedef __attribute__((ext_vector_type(4))) short short4v;
typedef __attribute__((ext_vector_type(4))) float f32x4;

// ---- Cl(3,1) sign helpers --------------------------------------------------
__device__ __forceinline__ float gp_sign(int a, int b) {
    int t = a >> 1, tot = 0;
    while (t) { tot += __popc(t & b); t >>= 1; }
    int neg = tot & 1;
    if ((a & b) & 8) neg ^= 1;   // METRIC[3] = -1
    return neg ? -1.f : 1.f;
}
__device__ __forceinline__ float rev_sign(int j) {
    int g = __popc(j);
    return ((g * (g - 1) / 2) & 1) ? -1.f : 1.f;
}
__device__ __forceinline__ ushort f2bf(float f) {
    unsigned int u = __float_as_uint(f);
    unsigned int r = (u + 0x7FFFu + ((u >> 16) & 1u)) >> 16;
    return (ushort)r;
}
__device__ __forceinline__ float bf2f(ushort h) {
    return __uint_as_float((unsigned int)h << 16);
}

// ---- embed gather + rotary bivector PE -------------------------------------
__global__ void embed_pe_kernel(const int* __restrict__ tok,
                                const float* __restrict__ embed,
                                float* __restrict__ x) {
    int idx = blockIdx.x * blockDim.x + threadIdx.x;
    if (idx >= BATCH * SEQ * NC) return;
    int c  = idx & (NC - 1);
    int bl = idx / NC;
    int l  = bl & (SEQ - 1);
    int t  = tok[bl];

    const float* e = embed + ((size_t)t * NC + c) * D16;
    float v[D16];
#pragma unroll
    for (int j = 0; j < D16; j++) v[j] = e[j];

    float freq = exp2f(-(float)c * (13.287712379549449f / (float)NC));
    float theta = (float)l * freq;
    float sn, cs;
    __sincosf(theta, &sn, &cs);

    float tmp[D16], out[D16];
#pragma unroll
    for (int k = 0; k < D16; k++)
        tmp[k] = cs * v[k] + sn * gp_sign(3, 3 ^ k) * v[3 ^ k];
#pragma unroll
    for (int k = 0; k < D16; k++)
        out[k] = cs * tmp[k] - sn * gp_sign(k ^ 3, 3) * tmp[k ^ 3];

    float* xp = x + (size_t)idx * D16;
#pragma unroll
    for (int j = 0; j < D16; j++) xp[j] = out[j];
}

// ---- split layer weights into bf16 hi/lo -----------------------------------
__global__ void split_lw(const float* __restrict__ wq, const float* __restrict__ wk,
                         const float* __restrict__ wv, const float* __restrict__ wo,
                         const float* __restrict__ up, const float* __restrict__ dn,
                         ushort* __restrict__ wsp) {
    int idx = blockIdx.x * 256 + threadIdx.x;
    if (idx >= 98304) return;
    const float* src; ushort *dh, *dl; int off;
    if (idx < 8192)       { src = wq; off = idx;         dh = wsp;          dl = wsp + 8192; }
    else if (idx < 16384) { src = wk; off = idx - 8192;  dh = wsp + 16384;  dl = wsp + 24576; }
    else if (idx < 24576) { src = wv; off = idx - 16384; dh = wsp + 32768;  dl = wsp + 40960; }
    else if (idx < 32768) { src = wo; off = idx - 24576; dh = wsp + 49152;  dl = wsp + 57344; }
    else if (idx < 65536) { src = up; off = idx - 32768; dh = wsp + 65536;  dl = wsp + 98304; }
    else                  { src = dn; off = idx - 65536; dh = wsp + 131072; dl = wsp + 163840; }
    float f = src[off];
    ushort hi = f2bf(f);
    dh[off] = hi;
    dl[off] = f2bf(f - bf2f(hi));
}

// ---- MFMA qkv: per-token [64o x 64c] x [64c x 16d]; CLN fused --------------
__global__ __launch_bounds__(256) void qkv_mfma_kernel(
        const float* __restrict__ x, const float* __restrict__ g,
        const ushort* __restrict__ wqh, const ushort* __restrict__ wql,
        const ushort* __restrict__ wkh, const ushort* __restrict__ wkl,
        const ushort* __restrict__ wvh, const ushort* __restrict__ wvl,
        ushort* __restrict__ qh_, ushort* __restrict__ ql_,
        ushort* __restrict__ kh_, ushort* __restrict__ kl_,
        float* __restrict__ v) {
    __shared__ float xlds[4][1024];
    __shared__ float glds[64];
    int t = threadIdx.x, wave = t >> 6, lane = t & 63;
    int tok = blockIdx.x * 4 + wave;
    if (t < 64) glds[t] = g[t];
    float ssum = 0.f;
    {
        const float* src = x + (size_t)tok * 1024 + lane * 16;
        float* dst = &xlds[wave][lane * 16];
#pragma unroll
        for (int i = 0; i < 4; i++) {
            float4 vv = *(const float4*)(src + i * 4);
            *(float4*)(dst + i * 4) = vv;
            ssum += vv.x * vv.x + vv.y * vv.y + vv.z * vv.z + vv.w * vv.w;
        }
    }
#pragma unroll
    for (int off = 32; off > 0; off >>= 1) ssum += __shfl_xor(ssum, off);
    float inv = 1.f / sqrtf(ssum * (1.f / 1024.f) + 1e-6f);
    __syncthreads();

    int dn = lane & 15, kg = lane >> 4;
    short8 bfh[2], bfl[2];
#pragma unroll
    for (int ks = 0; ks < 2; ks++) {
        int c0 = ks * 32 + kg * 8;
#pragma unroll
        for (int i = 0; i < 8; i++) {
            float val = xlds[wave][(c0 + i) * 16 + dn] * inv * glds[c0 + i];
            ushort hi = f2bf(val);
            bfh[ks][i] = (short)hi;
            bfl[ks][i] = (short)f2bf(val - bf2f(hi));
        }
    }
    float gs = gp_sign(dn, dn) * 0.088388347648318447f;

    const ushort* Wh[3] = { wqh, wkh, wvh };
    const ushort* Wl[3] = { wql, wkl, wvl };
#pragma unroll
    for (int m = 0; m < 3; m++) {
#pragma unroll
        for (int Mt = 0; Mt < 4; Mt++) {
            f32x4 acc = (f32x4){0.f, 0.f, 0.f, 0.f};
#pragma unroll
            for (int ks = 0; ks < 2; ks++) {
                size_t aoff = (size_t)(Mt * 16 + dn) * 64 + ks * 32 + kg * 8;
                short8 ah = *(const short8*)(Wh[m] + aoff);
                short8 al = *(const short8*)(Wl[m] + aoff);
                acc = __builtin_amdgcn_mfma_f32_16x16x32_bf16(ah, bfh[ks], acc, 0, 0, 0);
                acc = __builtin_amdgcn_mfma_f32_16x16x32_bf16(ah, bfl[ks], acc, 0, 0, 0);
                acc = __builtin_amdgcn_mfma_f32_16x16x32_bf16(al, bfh[ks], acc, 0, 0, 0);
            }
#pragma unroll
            for (int j = 0; j < 4; j++) {
                int o = Mt * 16 + kg * 4 + j;
                size_t oi = (size_t)tok * 1024 + o * 16 + dn;
                if (m == 0) {
                    float qv = acc[j] * gs;
                    ushort hi = f2bf(qv);
                    qh_[oi] = hi; ql_[oi] = f2bf(qv - bf2f(hi));
                } else if (m == 1) {
                    ushort hi = f2bf(acc[j]);
                    kh_[oi] = hi; kl_[oi] = f2bf(acc[j] - bf2f(hi));
                } else {
                    v[oi] = acc[j];
                }
            }
        }
    }
}

// ---- V transpose + bf16 split ----------------------------------------------
__global__ __launch_bounds__(256) void vtrans_kernel(
        const float* __restrict__ v,
        ushort* __restrict__ vth, ushort* __restrict__ vtl) {
    int bh = blockIdx.x;
    int lt = blockIdx.y;
    int b = bh >> 3, h = bh & 7;
    int t = threadIdx.x;
    __shared__ float tile[64 * 132];

    {
        int r = t >> 2, cb = (t & 3) * 32;
        const float* src = v + (size_t)(b * SEQ + lt * 64 + r) * 1024 + h * CHD + cb;
#pragma unroll
        for (int j = 0; j < 8; j++)
            *(float4*)&tile[r * 132 + cb + j * 4] = *(const float4*)(src + j * 4);
    }
    __syncthreads();

    int j = t >> 1, ib = (t & 1) * 32;
    size_t dst = (size_t)((b * 8 + h) * 128 + j) * 1024 + lt * 64 + ib;
#pragma unroll
    for (int u = 0; u < 4; u++) {
        short8 sh, sl;
#pragma unroll
        for (int e = 0; e < 8; e++) {
            float f = tile[(ib + u * 8 + e) * 132 + j];
            ushort hi = f2bf(f);
            sh[e] = (short)hi;
            sl[e] = (short)f2bf(f - bf2f(hi));
        }
        *(short8*)(vth + dst + u * 8) = sh;
        *(short8*)(vtl + dst + u * 8) = sl;
    }
}

// ---- MFMA flash attention with T14 register prefetch of next K/V tile ------
__global__ __launch_bounds__(256, 1) void attn_mfma_kernel(
        const ushort* __restrict__ qh_, const ushort* __restrict__ ql_,
        const ushort* __restrict__ kh_, const ushort* __restrict__ kl_,
        const ushort* __restrict__ vth, const ushort* __restrict__ vtl,
        float* __restrict__ o) {
    int qi = blockIdx.x;
    int bh = blockIdx.y;
    int b = bh >> 3, h = bh & 7;
    int t = threadIdx.x;
    int wave = t >> 6, lane = t & 63;
    int lq = lane & 15, lk4 = lane >> 4;

    __shared__ __align__(16) ushort Kh[64 * 128], Kl[64 * 128];
    __shared__ __align__(16) ushort Vh[128 * 64], Vl[128 * 64];
    __shared__ __align__(16) ushort Ph[4][16 * 80], Pl[4][16 * 80];

    int qrow = qi * 64 + wave * 16 + lq;

    short8 qfh[4], qfl[4];
    {
        const ushort* qb = qh_ + (size_t)(b * SEQ + qrow) * 1024 + h * CHD;
        const ushort* qb2 = ql_ + (size_t)(b * SEQ + qrow) * 1024 + h * CHD;
#pragma unroll
        for (int ks = 0; ks < 4; ks++) {
            qfh[ks] = *(const short8*)(qb + ks * 32 + lk4 * 8);
            qfl[ks] = *(const short8*)(qb2 + ks * 32 + lk4 * 8);
        }
    }

    // staging thread-geometry
    int kr = t >> 2, kcb = (t & 3) * 32;      // K: row, col-base
    int vr = t >> 1, vcb = (t & 1) * 32;      // V^T: row, col-base
    int kswz = (kr & 7) << 3, vswz = (vr & 7) << 3;

    short8 pk_h[4], pk_l[4], pv_h[4], pv_l[4];   // prefetch regs

    // prefetch tile 0
    {
        const ushort* sh_ = kh_ + (size_t)(b * SEQ + kr) * 1024 + h * CHD + kcb;
        const ushort* sl_ = kl_ + (size_t)(b * SEQ + kr) * 1024 + h * CHD + kcb;
#pragma unroll
        for (int j = 0; j < 4; j++) {
            pk_h[j] = *(const short8*)(sh_ + j * 8);
            pk_l[j] = *(const short8*)(sl_ + j * 8);
        }
        const ushort* vh_ = vth + (size_t)((b * 8 + h) * 128 + vr) * 1024 + vcb;
        const ushort* vl_ = vtl + (size_t)((b * 8 + h) * 128 + vr) * 1024 + vcb;
#pragma unroll
        for (int j = 0; j < 4; j++) {
            pv_h[j] = *(const short8*)(vh_ + j * 8);
            pv_l[j] = *(const short8*)(vl_ + j * 8);
        }
    }

    float m_run = -1e30f, l_run = 0.f;
    f32x4 oacc[8];
#pragma unroll
    for (int m = 0; m < 8; m++) oacc[m] = (f32x4){0.f, 0.f, 0.f, 0.f};

    int T = qi + 1;
    for (int kti = 0; kti < T; kti++) {
        __syncthreads();   // prev tile's LDS consumers done
        // regs -> LDS (swizzled)
#pragma unroll
        for (int j = 0; j < 4; j++) {
            int c8 = kcb + j * 8;
            *(short8*)&Kh[kr * 128 + (c8 ^ kswz)] = pk_h[j];
            *(short8*)&Kl[kr * 128 + (c8 ^ kswz)] = pk_l[j];
        }
#pragma unroll
        for (int j = 0; j < 4; j++) {
            int c8 = vcb + j * 8;
            *(short8*)&Vh[vr * 64 + (c8 ^ vswz)] = pv_h[j];
            *(short8*)&Vl[vr * 64 + (c8 ^ vswz)] = pv_l[j];
        }
        __syncthreads();

        // prefetch next tile (overlaps with MFMA below)
        if (kti + 1 < T) {
            const ushort* sh_ = kh_ + (size_t)(b * SEQ + (kti + 1) * 64 + kr) * 1024 + h * CHD + kcb;
            const ushort* sl_ = kl_ + (size_t)(b * SEQ + (kti + 1) * 64 + kr) * 1024 + h * CHD + kcb;
#pragma unroll
            for (int j = 0; j < 4; j++) {
                pk_h[j] = *(const short8*)(sh_ + j * 8);
                pk_l[j] = *(const short8*)(sl_ + j * 8);
            }
            const ushort* vh_ = vth + (size_t)((b * 8 + h) * 128 + vr) * 1024 + (kti + 1) * 64 + vcb;
            const ushort* vl_ = vtl + (size_t)((b * 8 + h) * 128 + vr) * 1024 + (kti + 1) * 64 + vcb;
#pragma unroll
            for (int j = 0; j < 4; j++) {
                pv_h[j] = *(const short8*)(vh_ + j * 8);
                pv_l[j] = *(const short8*)(vl_ + j * 8);
            }
        }

        f32x4 s[4];
#pragma unroll
        for (int kt = 0; kt < 4; kt++) s[kt] = (f32x4){0.f, 0.f, 0.f, 0.f};
#pragma unroll
        for (int kt = 0; kt < 4; kt++) {
            int rr = kt * 16 + lq;
            int rswz = (rr & 7) << 3;
#pragma unroll
            for (int ks = 0; ks < 4; ks++) {
                int idx = rr * 128 + ((ks * 32 + lk4 * 8) ^ rswz);
                short8 kfh = *(const short8*)&Kh[idx];
                short8 kfl = *(const short8*)&Kl[idx];
                s[kt] = __builtin_amdgcn_mfma_f32_16x16x32_bf16(kfh, qfh[ks], s[kt], 0, 0, 0);
                s[kt] = __builtin_amdgcn_mfma_f32_16x16x32_bf16(kfl, qfh[ks], s[kt], 0, 0, 0);
                s[kt] = __builtin_amdgcn_mfma_f32_16x16x32_bf16(kfh, qfl[ks], s[kt], 0, 0, 0);
            }
        }

        if (kti == qi) {
#pragma unroll
            for (int kt = 0; kt < 4; kt++)
#pragma unroll
                for (int r = 0; r < 4; r++) {
                    int kg = kti * 64 + kt * 16 + lk4 * 4 + r;
                    if (kg > qrow) s[kt][r] = -1e30f;
                }
        }

        float tm = -1e30f;
#pragma unroll
        for (int kt = 0; kt < 4; kt++)
#pragma unroll
            for (int r = 0; r < 4; r++) tm = fmaxf(tm, s[kt][r]);
        tm = fmaxf(tm, __shfl_xor(tm, 16));
        tm = fmaxf(tm, __shfl_xor(tm, 32));
        float mnew = fmaxf(m_run, tm);
        float corr = __expf(m_run - mnew);
        float ts = 0.f;
#pragma unroll
        for (int kt = 0; kt < 4; kt++) {
            float p0 = __expf(s[kt][0] - mnew);
            float p1 = __expf(s[kt][1] - mnew);
            float p2 = __expf(s[kt][2] - mnew);
            float p3 = __expf(s[kt][3] - mnew);
            ts += (p0 + p1) + (p2 + p3);
            short4v hi4, lo4;
            ushort u0 = f2bf(p0); hi4[0] = (short)u0; lo4[0] = (short)f2bf(p0 - bf2f(u0));
            ushort u1 = f2bf(p1); hi4[1] = (short)u1; lo4[1] = (short)f2bf(p1 - bf2f(u1));
            ushort u2 = f2bf(p2); hi4[2] = (short)u2; lo4[2] = (short)f2bf(p2 - bf2f(u2));
            ushort u3 = f2bf(p3); hi4[3] = (short)u3; lo4[3] = (short)f2bf(p3 - bf2f(u3));
            int pidx = lq * 80 + kt * 16 + lk4 * 4;
            *(short4v*)&Ph[wave][pidx] = hi4;
            *(short4v*)&Pl[wave][pidx] = lo4;
        }
        ts += __shfl_xor(ts, 16);
        ts += __shfl_xor(ts, 32);
        l_run = l_run * corr + ts;
        m_run = mnew;
#pragma unroll
        for (int m = 0; m < 8; m++) oacc[m] *= corr;

        short8 pfh[2], pfl[2];
#pragma unroll
        for (int ks = 0; ks < 2; ks++) {
            int pidx = lq * 80 + ks * 32 + lk4 * 8;
            pfh[ks] = *(const short8*)&Ph[wave][pidx];
            pfl[ks] = *(const short8*)&Pl[wave][pidx];
        }
#pragma unroll
        for (int m = 0; m < 8; m++) {
            int vrr = m * 16 + lq;
            int vsw = (vrr & 7) << 3;
#pragma unroll
            for (int ks = 0; ks < 2; ks++) {
                int idx = vrr * 64 + ((ks * 32 + lk4 * 8) ^ vsw);
                short8 vfh = *(const short8*)&Vh[idx];
                short8 vfl = *(const short8*)&Vl[idx];
                oacc[m] = __builtin_amdgcn_mfma_f32_16x16x32_bf16(vfh, pfh[ks], oacc[m], 0, 0, 0);
                oacc[m] = __builtin_amdgcn_mfma_f32_16x16x32_bf16(vfl, pfh[ks], oacc[m], 0, 0, 0);
                oacc[m] = __builtin_amdgcn_mfma_f32_16x16x32_bf16(vfh, pfl[ks], oacc[m], 0, 0, 0);
            }
        }
    }

    float invl = 1.f / l_run;
    float* ob = o + (size_t)(b * SEQ + qrow) * 1024 + h * CHD;
#pragma unroll
    for (int m = 0; m < 8; m++) {
        float4 w;
        w.x = oacc[m][0] * invl; w.y = oacc[m][1] * invl;
        w.z = oacc[m][2] * invl; w.w = oacc[m][3] * invl;
        *(float4*)(ob + m * 16 + lk4 * 4) = w;
    }
}

// ---- fused MFMA: wo-proj + residual + rms2 + Tmix-fold + FFN + residual ----
__global__ __launch_bounds__(256) void proj_ffn_mfma_kernel(
        const float* __restrict__ o_in,
        const ushort* __restrict__ woh, const ushort* __restrict__ wol,
        const float* __restrict__ g2, const float* __restrict__ Tmix,
        const ushort* __restrict__ uph, const ushort* __restrict__ upl,
        const ushort* __restrict__ dnh, const ushort* __restrict__ dnl,
        float* __restrict__ x) {
    __shared__ float olds[4][1024];
    __shared__ float xnlds[4][1024];
    __shared__ float g2lds[64];
    __shared__ float Ttlds[256];   // Tt[p*16+j] = Tmix[j*16+p]
    __shared__ ushort xmh[4][16][72], xml[4][16][72];
    __shared__ ushort ghh[4][16][72], ghl[4][16][72];
    int t = threadIdx.x, wave = t >> 6, lane = t & 63;
    int tok = blockIdx.x * 4 + wave;
    if (t < 64) g2lds[t] = g2[t];
    Ttlds[t] = Tmix[(t & 15) * 16 + (t >> 4)];
    {
        const float* src = o_in + (size_t)tok * 1024 + lane * 16;
        float* dst = &olds[wave][lane * 16];
#pragma unroll
        for (int i = 0; i < 4; i++)
            *(float4*)(dst + i * 4) = *(const float4*)(src + i * 4);
    }
    __syncthreads();

    int dn = lane & 15, kg = lane >> 4;
    short8 bfh[2], bfl[2];
#pragma unroll
    for (int ks = 0; ks < 2; ks++) {
        int c0 = ks * 32 + kg * 8;
#pragma unroll
        for (int i = 0; i < 8; i++) {
            float val = olds[wave][(c0 + i) * 16 + dn];
            ushort hi = f2bf(val);
            bfh[ks][i] = (short)hi;
            bfl[ks][i] = (short)f2bf(val - bf2f(hi));
        }
    }

    f32x4 C1[4];
#pragma unroll
    for (int Mt = 0; Mt < 4; Mt++) {
        f32x4 acc = (f32x4){0.f, 0.f, 0.f, 0.f};
#pragma unroll
        for (int ks = 0; ks < 2; ks++) {
            size_t aoff = (size_t)(Mt * 16 + dn) * 64 + ks * 32 + kg * 8;
            short8 ah = *(const short8*)(woh + aoff);
            short8 al = *(const short8*)(wol + aoff);
            acc = __builtin_amdgcn_mfma_f32_16x16x32_bf16(ah, bfh[ks], acc, 0, 0, 0);
            acc = __builtin_amdgcn_mfma_f32_16x16x32_bf16(ah, bfl[ks], acc, 0, 0, 0);
            acc = __builtin_amdgcn_mfma_f32_16x16x32_bf16(al, bfh[ks], acc, 0, 0, 0);
        }
        C1[Mt] = acc;
    }

    float ssum = 0.f;
#pragma unroll
    for (int Mt = 0; Mt < 4; Mt++) {
#pragma unroll
        for (int j = 0; j < 4; j++) {
            int o = Mt * 16 + kg * 4 + j;
            int idx = o * 16 + dn;
            float r = x[(size_t)tok * 1024 + idx] + C1[Mt][j];
            x[(size_t)tok * 1024 + idx] = r;
            xnlds[wave][idx] = r;
            ssum += r * r;
        }
    }
#pragma unroll
    for (int off = 32; off > 0; off >>= 1) ssum += __shfl_xor(ssum, off);
    float inv2 = 1.f / sqrtf(ssum * (1.f / 1024.f) + 1e-6f);
    __syncthreads();

    // xmix[p][c] = inv2*g2[c]*sum_j xn[c][j]*T[j][p] -> LDS (bf16 hi/lo)
    const float4* tr = (const float4*)&Ttlds[dn * 16];
    float4 t0 = tr[0], t1 = tr[1], t2 = tr[2], t3 = tr[3];
#pragma unroll
    for (int half = 0; half < 2; half++) {
        short8 xh, xl;
#pragma unroll
        for (int cc = 0; cc < 8; cc++) {
            int c = kg * 16 + half * 8 + cc;
            const float4* xr = (const float4*)&xnlds[wave][c * 16];
            float4 x0 = xr[0], x1 = xr[1], x2 = xr[2], x3 = xr[3];
            float dot = x0.x * t0.x + x0.y * t0.y + x0.z * t0.z + x0.w * t0.w
                      + x1.x * t1.x + x1.y * t1.y + x1.z * t1.z + x1.w * t1.w
                      + x2.x * t2.x + x2.y * t2.y + x2.z * t2.z + x2.w * t2.w
                      + x3.x * t3.x + x3.y * t3.y + x3.z * t3.z + x3.w * t3.w;
            float xm = dot * inv2 * g2lds[c];
            ushort hi = f2bf(xm);
            xh[cc] = (short)hi;
            xl[cc] = (short)f2bf(xm - bf2f(hi));
        }
        *(short8*)&xmh[wave][dn][kg * 16 + half * 8] = xh;
        *(short8*)&xml[wave][dn][kg * 16 + half * 8] = xl;
    }
    __syncthreads();

    // ---- FFN: up + gelu + down, e-chunked ----
    int p = dn;
    short8 bxh[2], bxl[2];
#pragma unroll
    for (int ks = 0; ks < 2; ks++) {
        bxh[ks] = *(const short8*)&xmh[wave][p][ks * 32 + kg * 8];
        bxl[ks] = *(const short8*)&xml[wave][p][ks * 32 + kg * 8];
    }

    f32x4 Cout[4];
#pragma unroll
    for (int m = 0; m < 4; m++) Cout[m] = (f32x4){0.f, 0.f, 0.f, 0.f};

    const float kA = 0.7978845608028654f;
#pragma unroll
    for (int ec = 0; ec < 4; ec++) {
        f32x4 accU[4];
#pragma unroll
        for (int mt = 0; mt < 4; mt++) {
            f32x4 acc = (f32x4){0.f, 0.f, 0.f, 0.f};
#pragma unroll
            for (int ks = 0; ks < 2; ks++) {
                size_t aoff = (size_t)(ec * 64 + mt * 16 + p) * 64 + ks * 32 + kg * 8;
                short8 ah = *(const short8*)(uph + aoff);
                short8 al = *(const short8*)(upl + aoff);
                acc = __builtin_amdgcn_mfma_f32_16x16x32_bf16(ah, bxh[ks], acc, 0, 0, 0);
                acc = __builtin_amdgcn_mfma_f32_16x16x32_bf16(ah, bxl[ks], acc, 0, 0, 0);
                acc = __builtin_amdgcn_mfma_f32_16x16x32_bf16(al, bxh[ks], acc, 0, 0, 0);
            }
            accU[mt] = acc;
        }
        __syncthreads();
#pragma unroll
        for (int mt = 0; mt < 4; mt++) {
#pragma unroll
            for (int j = 0; j < 4; j++) {
                int eloc = mt * 16 + kg * 4 + j;
                float u = accU[mt][j];
                float z = kA * (u + 0.044715f * u * u * u);
                float ex = __expf(2.f * z);
                float gg = u - u * (1.f / (ex + 1.f));
                ushort hi = f2bf(gg);
                ghh[wave][p][eloc] = hi;
                ghl[wave][p][eloc] = f2bf(gg - bf2f(hi));
            }
        }
        __syncthreads();
#pragma unroll
        for (int mto = 0; mto < 4; mto++) {
#pragma unroll
            for (int ks2 = 0; ks2 < 2; ks2++) {
                size_t aoff = (size_t)(mto * 16 + p) * 256 + ec * 64 + ks2 * 32 + kg * 8;
                short8 ah = *(const short8*)(dnh + aoff);
                short8 al = *(const short8*)(dnl + aoff);
                short8 bgh = *(const short8*)&ghh[wave][p][ks2 * 32 + kg * 8];
                short8 bgl = *(const short8*)&ghl[wave][p][ks2 * 32 + kg * 8];
                Cout[mto] = __builtin_amdgcn_mfma_f32_16x16x32_bf16(ah, bgh, Cout[mto], 0, 0, 0);
                Cout[mto] = __builtin_amdgcn_mfma_f32_16x16x32_bf16(ah, bgl, Cout[mto], 0, 0, 0);
                Cout[mto] = __builtin_amdgcn_mfma_f32_16x16x32_bf16(al, bgh, Cout[mto], 0, 0, 0);
            }
        }
    }

#pragma unroll
    for (int mto = 0; mto < 4; mto++) {
#pragma unroll
        for (int j = 0; j < 4; j++) {
            int o = mto * 16 + kg * 4 + j;
            size_t idx = (size_t)tok * 1024 + o * 16 + p;
            x[idx] = x[idx] + Cout[mto][j];
        }
    }
}

// ---- per-layer mixed rotor sandwich matrix Tmix[16][16] --------------------
__global__ void tmix_kernel(const float* __restrict__ rotor_biv,
                            const float* __restrict__ mixw,
                            float* __restrict__ Tmix) {
    int lay = blockIdx.x;
    __shared__ float rot[NK][D16];
    __shared__ float w[NK];
    int t = threadIdx.x;
    if (t < NK) {
        const int BIV[6] = { 3, 5, 6, 9, 10, 12 };
        float r[D16];
#pragma unroll
        for (int j = 0; j < D16; j++) r[j] = 0.f;
        r[0] = 1.f;
        float nrm = 1.f;
        for (int i = 0; i < 6; i++) {
            float bv = rotor_biv[(lay * NK + t) * 6 + i];
            r[BIV[i]] = bv; nrm += bv * bv;
        }
        nrm = sqrtf(nrm);
        for (int j = 0; j < D16; j++) rot[t][j] = r[j] / nrm;
    }
    if (t == 0) {
        float mx = -INFINITY;
        for (int kk = 0; kk < NK; kk++) mx = fmaxf(mx, mixw[lay * NK + kk]);
        float s = 0.f, e[NK];
        for (int kk = 0; kk < NK; kk++) { e[kk] = expf(mixw[lay * NK + kk] - mx); s += e[kk]; }
        for (int kk = 0; kk < NK; kk++) w[kk] = e[kk] / s;
    }
    __syncthreads();
    int j = t >> 4, p = t & 15;
    float acc = 0.f;
    for (int kk = 0; kk < NK; kk++) {
        float tk = 0.f;
        for (int i = 0; i < D16; i++) {
            int n = i ^ j ^ p;
            float rn = rot[kk][n] * rev_sign(n);
            tk += rot[kk][i] * rn * gp_sign(i, j) * gp_sign(i ^ j, n);
        }
        acc += w[kk] * tk;
    }
    Tmix[lay * 256 + t] = acc;
}

// ---- final norm + blade gate + grade-0; emit bf16 hi/lo --------------------
__global__ void g0_kernel(const float* __restrict__ x,
                          const float* __restrict__ g,
                          const float* __restrict__ sel,
                          ushort* __restrict__ g0h,
                          ushort* __restrict__ g0l) {
    int bl = blockIdx.x;
    const float* xr = x + (size_t)bl * 1024;
    __shared__ float red[256];
    float s = 0.f;
    for (int i = threadIdx.x; i < 1024; i += 256) { float v = xr[i]; s += v * v; }
    red[threadIdx.x] = s; __syncthreads();
    for (int st = 128; st > 0; st >>= 1) {
        if (threadIdx.x < st) red[threadIdx.x] += red[threadIdx.x + st];
        __syncthreads();
    }
    float inv = 1.f / sqrtf(red[0] * (1.f / 1024.f) + 1e-6f);
    if (threadIdx.x < NC) {
        int c = threadIdx.x;
        float gate = 1.f / (1.f + expf(-sel[c * D16]));
        float val = xr[c * D16] * inv * g[c] * gate;
        ushort hi = f2bf(val);
        g0h[(size_t)bl * NC + c] = hi;
        g0l[(size_t)bl * NC + c] = f2bf(val - bf2f(hi));
    }
}

// ---- head_w split into bf16 hi/lo ------------------------------------------
__global__ void split_hw(const float* __restrict__ hw,
                         ushort* __restrict__ hwh,
                         ushort* __restrict__ hwl) {
    int idx = blockIdx.x * blockDim.x + threadIdx.x;
    if (idx >= VOCAB * NC) return;
    float f = hw[idx];
    ushort hi = f2bf(f);
    hwh[idx] = hi;
    hwl[idx] = f2bf(f - bf2f(hi));
}

// ---- head GEMM: 64 rows x 256 vocab cols per block; 1KB/wave stores --------
// grid (125, 32); block 256 = 4 waves; wave computes 16 rows x 256 cols
__global__ __launch_bounds__(256) void head_mfma_kernel(
        const ushort* __restrict__ g0h, const ushort* __restrict__ g0l,
        const ushort* __restrict__ hwh, const ushort* __restrict__ hwl,
        const float* __restrict__ hb, float* __restrict__ out) {
    int t = threadIdx.x;
    int wave = t >> 6, lane = t & 63;
    int lr = lane & 15, lk = lane >> 4;
    int rowbase = blockIdx.y * 64 + wave * 16;
    int vbase = blockIdx.x * 256;

    __shared__ float tile[64 * 264];

    short8 ah[2], al[2];
#pragma unroll
    for (int ks = 0; ks < 2; ks++) {
        size_t off = (size_t)(rowbase + lr) * NC + ks * 32 + lk * 8;
        ah[ks] = *(const short8*)(g0h + off);
        al[ks] = *(const short8*)(g0l + off);
    }
    f32x4 acc[16];
#pragma unroll
    for (int nt = 0; nt < 16; nt++) acc[nt] = (f32x4){0.f, 0.f, 0.f, 0.f};

#pragma unroll
    for (int ks = 0; ks < 2; ks++) {
#pragma unroll
        for (int nt = 0; nt < 16; nt++) {
            size_t boff = (size_t)(vbase + nt * 16 + lr) * NC + ks * 32 + lk * 8;
            short8 bh = *(const short8*)(hwh + boff);
            short8 bl = *(const short8*)(hwl + boff);
            acc[nt] = __builtin_amdgcn_mfma_f32_16x16x32_bf16(ah[ks], bh, acc[nt], 0, 0, 0);
            acc[nt] = __builtin_amdgcn_mfma_f32_16x16x32_bf16(ah[ks], bl, acc[nt], 0, 0, 0);
            acc[nt] = __builtin_amdgcn_mfma_f32_16x16x32_bf16(al[ks], bh, acc[nt], 0, 0, 0);
        }
    }

    // stage 64x256 tile: block-local row = wave*16 + lk*4 + r, col = nt*16+lr
#pragma unroll
    for (int nt = 0; nt < 16; nt++)
#pragma unroll
        for (int r = 0; r < 4; r++)
            tile[(wave * 16 + lk * 4 + r) * 264 + nt * 16 + lr] = acc[nt][r];
    __syncthreads();

    // write-out: each wave writes one full 1KB row segment per iter
    float4 bias4 = *(const float4*)(hb + vbase + lane * 4);
#pragma unroll
    for (int iter = 0; iter < 16; iter++) {
        int row = iter * 4 + wave;
        float4 vv = *(const float4*)&tile[row * 264 + lane * 4];
        f32x4 sv;
        sv[0] = vv.x + bias4.x; sv[1] = vv.y + bias4.y;
        sv[2] = vv.z + bias4.z; sv[3] = vv.w + bias4.w;
        __builtin_nontemporal_store(sv,
            (f32x4*)(out + (size_t)(blockIdx.y * 64 + row) * VOCAB + vbase + lane * 4));
    }
}

extern "C" void kernel_launch(void* const* d_in, const int* in_sizes, int n_in,
                              void* d_out, int out_size, void* d_ws, size_t ws_size,
                              hipStream_t stream) {
    (void)in_sizes; (void)n_in; (void)out_size; (void)ws_size;
    const int*   tok      = (const int*)  d_in[0];
    const float* embed    = (const float*)d_in[1];
    const float* ln1_g    = (const float*)d_in[2];
    const float* ln2_g    = (const float*)d_in[3];
    const float* wq       = (const float*)d_in[4];
    const float* wk       = (const float*)d_in[5];
    const float* wv       = (const float*)d_in[6];
    const float* wo       = (const float*)d_in[7];
    const float* ffn_up   = (const float*)d_in[8];
    const float* ffn_down = (const float*)d_in[9];
    const float* rotor    = (const float*)d_in[10];
    const float* mixw     = (const float*)d_in[11];
    const float* out_ln_g = (const float*)d_in[12];
    const float* sel      = (const float*)d_in[13];
    const float* head_w   = (const float*)d_in[14];
    const float* head_b   = (const float*)d_in[15];
    float* out = (float*)d_out;

    float* ws  = (float*)d_ws;
    float* x    = ws;                         // 2,097,152 f
    float* o    = x + 2097152;                // 2,097,152 f
    float* vbuf = o + 2097152;                // 2,097,152 f
    float* Tmx  = vbuf + 2097152;             // 512 f
    ushort* qh   = (ushort*)(Tmx + 512);      // 2,097,152 us each
    ushort* ql   = qh + 2097152;
    ushort* kh   = ql + 2097152;
    ushort* kl   = kh + 2097152;
    ushort* vth  = kl + 2097152;
    ushort* vtl  = vth + 2097152;
    ushort* g0h  = vtl + 2097152;             // 131,072
    ushort* g0l  = g0h + 131072;
    ushort* hwh  = g0l + 131072;              // 2,048,000
    ushort* hwl  = hwh + 2048000;
    ushort* wsp  = hwl + 2048000;             // 196,608

    embed_pe_kernel<<<(BATCH * SEQ * NC + 255) / 256, 256, 0, stream>>>(tok, embed, x);
    tmix_kernel<<<NLAY, 256, 0, stream>>>(rotor, mixw, Tmx);
    split_hw<<<(VOCAB * NC + 255) / 256, 256, 0, stream>>>(head_w, hwh, hwl);
    split_lw<<<384, 256, 0, stream>>>(wq, wk, wv, wo, ffn_up, ffn_down, wsp);

    for (int l = 0; l < NLAY; l++) {
        int lo = l * 4096;
        int le = l * 16384;
        qkv_mfma_kernel<<<512, 256, 0, stream>>>(
            x, ln1_g + l * NC,
            wsp + lo, wsp + 8192 + lo, wsp + 16384 + lo, wsp + 24576 + lo,
            wsp + 32768 + lo, wsp + 40960 + lo,
            qh, ql, kh, kl, vbuf);
        dim3 vg(16, 16);
        vtrans_kernel<<<vg, 256, 0, stream>>>(vbuf, vth, vtl);
        dim3 ag(16, 16);
        attn_mfma_kernel<<<ag, 256, 0, stream>>>(qh, ql, kh, kl, vth, vtl, o);
        proj_ffn_mfma_kernel<<<512, 256, 0, stream>>>(
            o, wsp + 49152 + lo, wsp + 57344 + lo,
            ln2_g + l * NC, Tmx + l * 256,
            wsp + 65536 + le, wsp + 98304 + le,
            wsp + 131072 + le, wsp + 163840 + le, x);
    }

    g0_kernel<<<BATCH * SEQ, 256, 0, stream>>>(x, out_ln_g, sel, g0h, g0l);
    dim3 hg(VOCAB / 256, (BATCH * SEQ) / 64);   // (125, 32)
    head_mfma_kernel<<<hg, 256, 0, stream>>>(g0h, g0l, hwh, hwl, head_b, out);
}